// Round 8
// baseline (213.072 us; speedup 1.0000x reference)
//
#include <hip/hip_runtime.h>
#include <math.h>

#define EPS_F 1e-7f

constexpr int ROWS  = 32 * 8192;               // 262144 (B*T)
constexpr int BLOCK = 128;                     // 2 waves/block
constexpr int TILE_ITEMS = 128;                // one vec4 item per thread per tile
constexpr int NT    = (ROWS * 4) / TILE_ITEMS; // 8192 tiles
constexpr int GRID  = 768;                     // 3 blocks/CU (persistent)
constexpr int KIT   = (NT + GRID - 1) / GRID;  // 11 iterations per block

// Per-buffer LDS layout (bytes). 8 x 2KB vec arrays + 6KB clog + 2 x 256B.
constexpr int R_OCID = 0 * 2048;
constexpr int R_OCAN = 1 * 2048;
constexpr int R_OFIR = 2 * 2048;
constexpr int R_OVAL = 3 * 2048;
constexpr int R_CID  = 4 * 2048;
constexpr int R_LIVE = 5 * 2048;
constexpr int R_TRIG = 6 * 2048;
constexpr int R_VALP = 7 * 2048;
constexpr int R_CLOG = 8 * 2048;               // 6144 B
constexpr int R_WSC  = R_CLOG + 6144;          // 256 B (wave0 stages)
constexpr int R_OSW  = R_WSC + 256;            // 256 B (wave1 stages)
constexpr int BUFSZ  = R_OSW + 256;            // 23040 B
// 2 buffers = 46080 B -> 3 blocks/CU on 160KB LDS.

// s_waitcnt immediates (gfx9 encoding: vmcnt[3:0]|exp[6:4]|lgkm[11:8]|vmcnt[5:4]<<14)
#define WAIT_VM12 0x0F7C   // vmcnt<=12, lgkm/exp don't-care
#define WAIT_VM0  0x0F70   // vmcnt<=0

typedef unsigned long long u64;

__device__ __forceinline__ u64 shflx64(u64 v, int m) {
  unsigned lo = __shfl_xor((unsigned)v, m, 64);
  unsigned hi = __shfl_xor((unsigned)(v >> 32), m, 64);
  return ((u64)hi << 32) | lo;
}

// Async global->LDS DMA: LDS base wave-uniform, HW scatters lane i -> base+i*size.
__device__ __forceinline__ void dma16(void* lds, const void* g) {
  __builtin_amdgcn_global_load_lds(
      (const __attribute__((address_space(1))) void*)g,
      (__attribute__((address_space(3))) void*)lds, 16, 0, 0);
}
__device__ __forceinline__ void dma4(void* lds, const void* g) {
  __builtin_amdgcn_global_load_lds(
      (const __attribute__((address_space(1))) void*)g,
      (__attribute__((address_space(3))) void*)lds, 4, 0, 0);
}

__global__ __launch_bounds__(BLOCK) void loss_main(
    const float* __restrict__ trig,
    const float* __restrict__ valp,
    const float* __restrict__ clog,
    const float* __restrict__ wscore,
    const int*   __restrict__ live,
    const int*   __restrict__ cid,
    const float* __restrict__ ofire,
    const int*   __restrict__ ocan,
    const float* __restrict__ ovalid,
    const float* __restrict__ oshw,
    const int*   __restrict__ ocid,
    float* __restrict__ part)            // [GRID][6]
{
  __shared__ __align__(16) char smem[2 * BUFSZ];

  const int tid  = threadIdx.x;
  const int lane = tid & 63;
  const int w    = tid >> 6;             // wave 0/1

  float s0 = 0.f, s1 = 0.f, s2 = 0.f, s3 = 0.f, s4 = 0.f, s5 = 0.f;

  // Stage one tile's data for THIS wave only (12 DMAs, wave-private LDS
  // slices -> no cross-wave deps -> no __syncthreads in the loop).
  auto stage = [&](int tileC, int bufIdx) {
    char* buf = smem + bufIdx * BUFSZ;
    char* sb  = buf + w * 1024;
    const int gi = tileC * TILE_ITEMS + w * 64 + lane;   // vec4 item
    const size_t o16 = (size_t)gi * 16;
    dma16(sb + R_OCID, (const char*)ocid  + o16);
    dma16(sb + R_OCAN, (const char*)ocan  + o16);
    dma16(sb + R_OFIR, (const char*)ofire + o16);
    dma16(sb + R_OVAL, (const char*)ovalid+ o16);
    dma16(sb + R_CID,  (const char*)cid   + o16);
    dma16(sb + R_LIVE, (const char*)live  + o16);
    dma16(sb + R_TRIG, (const char*)trig  + o16);
    dma16(sb + R_VALP, (const char*)valp  + o16);
    const char* gc = (const char*)clog + (size_t)(tileC * TILE_ITEMS + w * 64) * 48;
    char* sc = buf + R_CLOG + w * 3072;
    dma16(sc + 0,    gc + 0    + lane * 16);
    dma16(sc + 1024, gc + 1024 + lane * 16);
    dma16(sc + 2048, gc + 2048 + lane * 16);
    // row scalars ride the DMA stream too (keeps vmcnt bookkeeping exact):
    // wave0 -> wscore, wave1 -> oshw. 64 lanes stage 64 rows (32 used).
    const int row = min(tileC * 32 + lane, ROWS - 1);
    if (w == 0) dma4(buf + R_WSC, (const char*)wscore + (size_t)row * 4);
    else        dma4(buf + R_OSW, (const char*)oshw   + (size_t)row * 4);
  };

  auto compute = [&](int bufIdx) {
    const char* buf = smem + bufIdx * BUFSZ;
    const int4   oc = *(const int4*)  (buf + R_OCID + tid * 16);
    const int4   cc = *(const int4*)  (buf + R_OCAN + tid * 16);
    const float4 ff = *(const float4*)(buf + R_OFIR + tid * 16);
    const float4 vv = *(const float4*)(buf + R_OVAL + tid * 16);
    const int4   cd = *(const int4*)  (buf + R_CID  + tid * 16);
    const int4   lm = *(const int4*)  (buf + R_LIVE + tid * 16);
    const float4 ph = *(const float4*)(buf + R_TRIG + tid * 16);
    const float4 pq = *(const float4*)(buf + R_VALP + tid * 16);
    const float4 lA = *(const float4*)(buf + R_CLOG + tid * 48 + 0);
    const float4 lB = *(const float4*)(buf + R_CLOG + tid * 48 + 16);
    const float4 lC = *(const float4*)(buf + R_CLOG + tid * 48 + 32);
    const float  wx = *(const float*) (buf + R_WSC + (tid >> 2) * 4);
    const float  wy = *(const float*) (buf + R_OSW + (tid >> 2) * 4);

    // per-lane partial oracle table (my 4 slots, slot order)
    u64 tblLo = 0ull, tblHi = 0ull, fndLo = 0ull, fndHi = 0ull;
    {
      const int   ocs[4] = {oc.x, oc.y, oc.z, oc.w};
      const int   ccs[4] = {cc.x, cc.y, cc.z, cc.w};
      const float ffs[4] = {ff.x, ff.y, ff.z, ff.w};
      const float vvs[4] = {vv.x, vv.y, vv.z, vv.w};
      #pragma unroll
      for (int j = 0; j < 4; ++j) {
        const unsigned c  = (unsigned)ocs[j] & 31u;
        const unsigned sh = (c & 15u) * 4u;
        const bool isLo   = c < 16u;
        const bool seen   = (((isLo ? fndLo : fndHi) >> sh) & 1ull) != 0ull;
        const unsigned nib = (unsigned)ffs[j] | ((unsigned)vvs[j] << 1) |
                             ((unsigned)ccs[j] << 2);
        const u64 add  = seen ? 0ull : ((u64)nib << sh);
        const u64 fadd = 0xFull << sh;
        tblLo |= isLo ? add : 0ull;
        tblHi |= isLo ? 0ull : add;
        fndLo |= isLo ? fadd : 0ull;
        fndHi |= isLo ? 0ull : fadd;
      }
    }
    // merge across 4-lane row group (lower lane = earlier slot wins)
    #pragma unroll
    for (int m = 1; m <= 2; m <<= 1) {
      const u64 pTL = shflx64(tblLo, m);
      const u64 pTH = shflx64(tblHi, m);
      const u64 pFL = shflx64(fndLo, m);
      const u64 pFH = shflx64(fndHi, m);
      const bool iLow = (lane & m) == 0;
      const u64 loTL = iLow ? tblLo : pTL, hiTL = iLow ? pTL : tblLo;
      const u64 loTH = iLow ? tblHi : pTH, hiTH = iLow ? pTH : tblHi;
      const u64 loFL = iLow ? fndLo : pFL, hiFL = iLow ? pFL : fndLo;
      const u64 loFH = iLow ? fndHi : pFH, hiFH = iLow ? pFH : fndHi;
      tblLo = loTL | (hiTL & ~loFL);
      tblHi = loTH | (hiTH & ~loFH);
      fndLo = loFL | hiFL;
      fndHi = loFH | hiFH;
    }
    // losses for my 4 slots
    {
      const int   cds[4] = {cd.x, cd.y, cd.z, cd.w};
      const int   lms[4] = {lm.x, lm.y, lm.z, lm.w};
      const float phs[4] = {ph.x, ph.y, ph.z, ph.w};
      const float pqs[4] = {pq.x, pq.y, pq.z, pq.w};
      const float L0[4] = {lA.x, lA.w, lB.z, lC.y};
      const float L1[4] = {lA.y, lB.x, lB.w, lC.z};
      const float L2[4] = {lA.z, lB.y, lC.x, lC.w};
      #pragma unroll
      for (int j = 0; j < 4; ++j) {
        const unsigned c  = (unsigned)cds[j] & 31u;
        const unsigned sh = (c & 15u) * 4u;
        const bool isLo   = c < 16u;
        const bool fnd = (c != 0u) &&
                         ((((isLo ? fndLo : fndHi) >> sh) & 1ull) != 0ull);
        unsigned nib = (unsigned)(((isLo ? tblLo : tblHi) >> sh)) & 15u;
        nib = fnd ? nib : 0u;
        const float fire_t = (float)(nib & 1u);
        const float val_t  = (float)((nib >> 1) & 1u);
        const int   can_t  = (int)(nib >> 2);

        const float m = lms[j] ? 1.f : 0.f;

        const float p  = fminf(fmaxf(phs[j], EPS_F), 1.f - EPS_F);
        const float bf = -__logf((fire_t != 0.f) ? p : 1.f - p);
        const float q  = fminf(fmaxf(pqs[j], EPS_F), 1.f - EPS_F);
        const float bv = -__logf((val_t != 0.f) ? q : 1.f - q);

        const float has = (can_t > 0 && lms[j]) ? 1.f : 0.f;
        const int tgt = (can_t - 1) < 0 ? 0 : (can_t - 1);
        const float l0 = L0[j], l1 = L1[j], l2 = L2[j];
        const float mx  = fmaxf(l0, fmaxf(l1, l2));
        const float lse = mx + __logf(__expf(l0 - mx) + __expf(l1 - mx) +
                                      __expf(l2 - mx));
        const float lt  = (tgt == 0) ? l0 : ((tgt == 1) ? l1 : l2);

        s0 += bf * m;
        s1 += m;
        s2 += (lse - lt) * has;
        s3 += has;
        s4 += bv * m;
      }
    }
    if ((tid & 3) == 0) {
      s5 += fmaxf(wx, 0.f) - wx * wy + __logf(1.f + __expf(-fabsf(wx)));
    }
  };

  // ---- persistent pipeline: block b owns tiles b, b+GRID, ..., b+(KIT-1)*GRID
  const int b = blockIdx.x;
  auto tileOf = [&](int k) { return b + k * GRID; };
  auto tileC  = [&](int k) { int t = tileOf(k); return t < NT ? t : NT - 1; };

  stage(tileC(0), 0);          // 12 DMAs/wave in flight
  stage(tileC(1), 1);          // 24 in flight
  for (int k = 0; k < KIT; ++k) {
    // wait until <=12 outstanding: tile k's 12 (oldest) have landed while
    // tile k+1's 12 STAY IN FLIGHT across the consume -- the mechanism no
    // prior round could express (syncthreads would vmcnt(0)-drain them).
    if (k == KIT - 1) __builtin_amdgcn_s_waitcnt(WAIT_VM0);
    else              __builtin_amdgcn_s_waitcnt(WAIT_VM12);
    __builtin_amdgcn_sched_barrier(0);   // no ds_read may hoist above the wait
    if (tileOf(k) < NT) compute(k & 1);  // uniform branch; pad tiles skipped
    __builtin_amdgcn_sched_barrier(0);   // DMA reuse of this buf stays below
    if (k + 2 < KIT) stage(tileC(k + 2), k & 1);
  }

  // ---- wave reduce, then block reduce via LDS
  float v[6] = {s0, s1, s2, s3, s4, s5};
  #pragma unroll
  for (int off = 32; off > 0; off >>= 1) {
    #pragma unroll
    for (int i = 0; i < 6; ++i) v[i] += __shfl_down(v[i], off, 64);
  }
  __shared__ float red[2][6];
  if (lane == 0) {
    #pragma unroll
    for (int i = 0; i < 6; ++i) red[w][i] = v[i];
  }
  __syncthreads();
  if (tid == 0) {
    #pragma unroll
    for (int i = 0; i < 6; ++i)
      part[b * 6 + i] = red[0][i] + red[1][i];
  }
}

// Reduce GRID partials in double, compute the 5 outputs.
__global__ __launch_bounds__(256) void loss_finalize(
    const float* __restrict__ part, float* __restrict__ out)
{
  double v[6] = {0, 0, 0, 0, 0, 0};
  for (int r = threadIdx.x; r < GRID; r += 256) {
    #pragma unroll
    for (int i = 0; i < 6; ++i) v[i] += (double)part[r * 6 + i];
  }
  #pragma unroll
  for (int off = 32; off > 0; off >>= 1) {
    #pragma unroll
    for (int i = 0; i < 6; ++i) v[i] += __shfl_down(v[i], off, 64);
  }
  __shared__ double red[4][6];
  const int w = threadIdx.x >> 6, lane = threadIdx.x & 63;
  if (lane == 0) {
    #pragma unroll
    for (int i = 0; i < 6; ++i) red[w][i] = v[i];
  }
  __syncthreads();
  if (threadIdx.x == 0) {
    double a[6];
    #pragma unroll
    for (int i = 0; i < 6; ++i) a[i] = red[0][i] + red[1][i] + red[2][i] + red[3][i];
    const double live_n = a[1] < 1.0 ? 1.0 : a[1];
    const double fire   = a[0] / live_n;                                   // LAM_FIRE   = 1.0
    const double cancel = (a[3] > 0.0) ? a[2] / (a[3] < 1.0 ? 1.0 : a[3])  // LAM_CANCEL = 1.0
                                       : 0.0;
    const double valid  = 0.5 * a[4] / live_n;                             // LAM_VALID  = 0.5
    const double wr     = 0.5 * a[5] / (double)ROWS;                       // LAM_WRITE  = 0.5
    out[0] = (float)fire;
    out[1] = (float)cancel;
    out[2] = (float)valid;
    out[3] = (float)wr;
    out[4] = (float)(fire + cancel + valid + wr);
  }
}

extern "C" void kernel_launch(void* const* d_in, const int* in_sizes, int n_in,
                              void* d_out, int out_size, void* d_ws, size_t ws_size,
                              hipStream_t stream) {
  const float* trig   = (const float*)d_in[0];
  const float* valp   = (const float*)d_in[1];
  const float* clog   = (const float*)d_in[2];
  const float* wscore = (const float*)d_in[3];
  const int*   live   = (const int*)  d_in[4];
  const int*   cid    = (const int*)  d_in[5];
  const float* ofire  = (const float*)d_in[6];
  const int*   ocan   = (const int*)  d_in[7];
  const float* ovalid = (const float*)d_in[8];
  const float* oshw   = (const float*)d_in[9];
  const int*   ocid   = (const int*)  d_in[10];
  float* out  = (float*)d_out;
  float* part = (float*)d_ws;   // GRID*6 floats = 18 KB, fully overwritten

  loss_main<<<GRID, BLOCK, 0, stream>>>(trig, valp, clog, wscore, live, cid,
                                        ofire, ocan, ovalid, oshw, ocid, part);
  loss_finalize<<<1, 256, 0, stream>>>(part, out);
}